// Round 1
// baseline (416.402 us; speedup 1.0000x reference)
//
#include <hip/hip_runtime.h>

#define WIDTH 1024
#define BW 64
#define NB 16
#define ROWS_PER_WG 8
#define HPAD 68                       // 64 + 4 pad: breaks stride-64 bank aliasing, keeps 16B align
#define ROWSTRIDE (NB * HPAD)         // 1088 floats per staged row

__device__ __forceinline__ void fma4(float4& a, float s, const float4& w) {
    a.x = fmaf(s, w.x, a.x);
    a.y = fmaf(s, w.y, a.y);
    a.z = fmaf(s, w.z, a.z);
    a.w = fmaf(s, w.w, a.w);
}

__global__ __launch_bounds__(256, 4)
void griffin_gate_kernel(const float* __restrict__ x,
                         const float* __restrict__ ln_scale,
                         const float* __restrict__ ln_bias,
                         const float* __restrict__ w,
                         const float* __restrict__ b,
                         const float* __restrict__ a_param,
                         float* __restrict__ alpha_out,
                         float* __restrict__ beta_out)
{
    __shared__ float xn_s[ROWS_PER_WG * ROWSTRIDE];   // 34816 B

    const int t    = threadIdx.x;
    const int wave = t >> 6;
    const int lane = t & 63;
    const long long row_base = (long long)blockIdx.x * ROWS_PER_WG;

    // ---------- Phase 1: LayerNorm + stage to LDS. Each wave owns 2 rows. ----------
    // lane covers cols {256k + 4*lane .. +3}, k = 0..3 (perfectly coalesced float4)
    float4 sc[4], bi[4];
#pragma unroll
    for (int k = 0; k < 4; ++k) {
        sc[k] = *(const float4*)(ln_scale + 256 * k + 4 * lane);
        bi[k] = *(const float4*)(ln_bias  + 256 * k + 4 * lane);
    }

#pragma unroll
    for (int rr = 0; rr < 2; ++rr) {
        const int r = wave * 2 + rr;
        const float* xrow = x + (row_base + r) * WIDTH;
        float4 v[4];
        float s = 0.f, s2 = 0.f;
#pragma unroll
        for (int k = 0; k < 4; ++k) {
            v[k] = *(const float4*)(xrow + 256 * k + 4 * lane);
            s += v[k].x + v[k].y + v[k].z + v[k].w;
            s2 = fmaf(v[k].x, v[k].x, s2);
            s2 = fmaf(v[k].y, v[k].y, s2);
            s2 = fmaf(v[k].z, v[k].z, s2);
            s2 = fmaf(v[k].w, v[k].w, s2);
        }
        // wave64 butterfly reduce (no LDS, no cross-wave sync needed)
#pragma unroll
        for (int off = 32; off >= 1; off >>= 1) {
            s  += __shfl_xor(s,  off, 64);
            s2 += __shfl_xor(s2, off, 64);
        }
        const float mean = s * (1.0f / WIDTH);
        const float var  = fmaxf(s2 * (1.0f / WIDTH) - mean * mean, 0.0f);
        const float rstd = rsqrtf(var + 1e-6f);
#pragma unroll
        for (int k = 0; k < 4; ++k) {
            float4 xn;
            xn.x = fmaf((v[k].x - mean) * rstd, sc[k].x, bi[k].x);
            xn.y = fmaf((v[k].y - mean) * rstd, sc[k].y, bi[k].y);
            xn.z = fmaf((v[k].z - mean) * rstd, sc[k].z, bi[k].z);
            xn.w = fmaf((v[k].w - mean) * rstd, sc[k].w, bi[k].w);
            const int h     = 4 * k + (lane >> 4);      // which 64-wide block
            const int inner = 4 * (lane & 15);          // offset within block
            *(float4*)(&xn_s[r * ROWSTRIDE + h * HPAD + inner]) = xn;
        }
    }
    __syncthreads();

    // ---------- Phase 2: block-diagonal matmul. Thread t computes cols 4t..4t+3 for all 8 rows. ----------
    const int h  = t >> 4;           // block 0..15  (h*64 + jl == 4t)
    const int jl = (t & 15) * 4;
    const float* wh = w + h * (BW * BW) + jl;          // w[h][i][jl..jl+3], L1/L2-resident
    const float4 bias4 = *(const float4*)(b + h * BW + jl);
    float4 acc[ROWS_PER_WG];
#pragma unroll
    for (int r = 0; r < ROWS_PER_WG; ++r) acc[r] = bias4;

    const float* xs = xn_s + h * HPAD;
#pragma unroll 4
    for (int i4 = 0; i4 < 16; ++i4) {
        const float* wp = wh + i4 * 4 * BW;
        const float4 w0 = *(const float4*)(wp);
        const float4 w1 = *(const float4*)(wp + BW);
        const float4 w2 = *(const float4*)(wp + 2 * BW);
        const float4 w3 = *(const float4*)(wp + 3 * BW);
#pragma unroll
        for (int r = 0; r < ROWS_PER_WG; ++r) {
            // 16-lane broadcast read, groups land on disjoint 4-bank slots (HPAD=68)
            const float4 xq = *(const float4*)(xs + r * ROWSTRIDE + i4 * 4);
            fma4(acc[r], xq.x, w0);
            fma4(acc[r], xq.y, w1);
            fma4(acc[r], xq.z, w2);
            fma4(acc[r], xq.w, w3);
        }
    }

    // ---------- Phase 3: gate chain + store ----------
    const float4 ap = *(const float4*)(a_param + h * BW + jl);
    float4 sp;   // softplus(a_param); a_param in [-6.9, -2.2] so expf safe
    sp.x = log1pf(__expf(ap.x));
    sp.y = log1pf(__expf(ap.y));
    sp.z = log1pf(__expf(ap.z));
    sp.w = log1pf(__expf(ap.w));

    float* aout = alpha_out + row_base * WIDTH + 4 * t;
    float* bout = beta_out  + row_base * WIDTH + 4 * t;
#pragma unroll
    for (int r = 0; r < ROWS_PER_WG; ++r) {
        const float4 g = acc[r];
        float4 al;
        al.x = __expf(-8.0f * sp.x * __builtin_amdgcn_rcpf(1.0f + __expf(-g.x)));
        al.y = __expf(-8.0f * sp.y * __builtin_amdgcn_rcpf(1.0f + __expf(-g.y)));
        al.z = __expf(-8.0f * sp.z * __builtin_amdgcn_rcpf(1.0f + __expf(-g.z)));
        al.w = __expf(-8.0f * sp.w * __builtin_amdgcn_rcpf(1.0f + __expf(-g.w)));
        al.x = fminf(fmaxf(al.x, 0.05f), 0.95f);
        al.y = fminf(fmaxf(al.y, 0.05f), 0.95f);
        al.z = fminf(fmaxf(al.z, 0.05f), 0.95f);
        al.w = fminf(fmaxf(al.w, 0.05f), 0.95f);
        const float4 be = make_float4(1.0f - al.x, 1.0f - al.y, 1.0f - al.z, 1.0f - al.w);
        *(float4*)(aout + (long long)r * WIDTH) = al;
        *(float4*)(bout + (long long)r * WIDTH) = be;
    }
}

extern "C" void kernel_launch(void* const* d_in, const int* in_sizes, int n_in,
                              void* d_out, int out_size, void* d_ws, size_t ws_size,
                              hipStream_t stream)
{
    const float* x        = (const float*)d_in[0];
    const float* ln_scale = (const float*)d_in[1];
    const float* ln_bias  = (const float*)d_in[2];
    const float* w        = (const float*)d_in[3];
    const float* b        = (const float*)d_in[4];
    const float* a_param  = (const float*)d_in[5];

    const long long total = (long long)in_sizes[0];        // 4*8192*1024
    const long long rows  = total / WIDTH;                 // 32768
    float* alpha_out = (float*)d_out;
    float* beta_out  = alpha_out + total;

    const int grid = (int)(rows / ROWS_PER_WG);            // 4096
    griffin_gate_kernel<<<grid, 256, 0, stream>>>(x, ln_scale, ln_bias, w, b, a_param,
                                                  alpha_out, beta_out);
}